// Round 1
// baseline (1005.554 us; speedup 1.0000x reference)
//
#include <hip/hip_runtime.h>

#define Bn 4
#define Cn 128
#define Nn 65536
#define KT 9
#define T_OUT 56
#define T_HALO 64
#define TILES_PB 1171   // ceil(65536/56)
#define XROW 136        // f16 elems per LDS X row (128 + 8 pad) = 272 B
#define YSTR 69         // f32 elems per LDS Y row (64 + 5 pad)

typedef _Float16 f16x8 __attribute__((ext_vector_type(8)));
typedef float f32x4 __attribute__((ext_vector_type(4)));

__device__ __forceinline__ int imin(int a, int b) { return a < b ? a : b; }

// ---------------- repack weights: [O][C][K] f32 -> [t][o][c] f16 ----------------
__global__ __launch_bounds__(256) void repack_w(const float* __restrict__ w1,
                                                const float* __restrict__ w2,
                                                _Float16* __restrict__ Wr) {
  int i = blockIdx.x * 256 + threadIdx.x;  // [cv][t][o][c], total 2*9*128*128
  int c = i & 127;
  int o = (i >> 7) & 127;
  int t = (i >> 14) % KT;
  int cv = i / (KT << 14);
  const float* w = cv ? w2 : w1;
  Wr[i] = (_Float16)w[(o * 128 + c) * KT + t];
}

// ---------------- gather x into curve order, f16, channel-contiguous rows ------
__global__ __launch_bounds__(256) void gather_x(const float* __restrict__ x,
                                                const int* __restrict__ reidx,
                                                _Float16* __restrict__ xp) {
  __shared__ __align__(16) _Float16 tile[T_HALO * XROW];
  int tid = threadIdx.x;
  int b = blockIdx.x >> 10;
  int n0 = (blockIdx.x & 1023) * 64;
  int j = tid & 63;
  int cw = tid >> 6;
  const float* xb = x + (size_t)b * Cn * Nn;
  for (int ci = 0; ci < 32; ++ci) {
    int c = ci * 4 + cw;
    float v = xb[(size_t)c * Nn + n0 + j];      // coalesced over j
    tile[j * XROW + c] = (_Float16)v;           // LDS transpose
  }
  __syncthreads();
  int ch = tid & 15;
#pragma unroll
  for (int pass = 0; pass < 4; ++pass) {
    int r = pass * 16 + (tid >> 4);
    int m = reidx[(size_t)b * Nn + n0 + r];
    f16x8 v = *(const f16x8*)(&tile[r * XROW + ch * 8]);
    *(f16x8*)(xp + ((size_t)b * Nn + m) * Cn + ch * 8) = v;  // 256B row scatter
  }
}

// ---------------- gather coords into curve order (planar) ----------------------
__global__ __launch_bounds__(256) void gather_cp(const float* __restrict__ coords,
                                                 const int* __restrict__ indices,
                                                 float* __restrict__ cp) {
  int gidx = blockIdx.x * 256 + threadIdx.x;  // b*N + m
  int b = gidx >> 16;
  int m = gidx & (Nn - 1);
  int idx = indices[gidx];
  const float* cb = coords + (size_t)b * 3 * Nn;
  float* cpb = cp + (size_t)b * 3 * Nn;
  cpb[m] = cb[idx];
  cpb[Nn + m] = cb[Nn + idx];
  cpb[2 * Nn + m] = cb[2 * Nn + idx];
}

// ---------------- gaussian tap weights g[b][t][m] ------------------------------
__global__ __launch_bounds__(256) void compute_g(const float* __restrict__ cp,
                                                 float* __restrict__ G) {
  int gidx = blockIdx.x * 256 + threadIdx.x;
  int b = gidx >> 16;
  int m = gidx & (Nn - 1);
  const float* cpb = cp + (size_t)b * 3 * Nn;
  float x0 = cpb[m], y0 = cpb[Nn + m], z0 = cpb[2 * Nn + m];
  float* Gb = G + (size_t)b * KT * Nn;
#pragma unroll
  for (int t = 0; t < KT; ++t) {
    int q = m + t - 4;
    q = q < 0 ? 0 : (q > Nn - 1 ? Nn - 1 : q);  // OOB value irrelevant (x==0 there)
    float dx = cpb[q] - x0;
    float dy = cpb[Nn + q] - y0;
    float dz = cpb[2 * Nn + q] - z0;
    Gb[(size_t)t * Nn + m] = __expf(-(dx * dx + dy * dy + dz * dz));  // sigma=1
  }
}

// ---------------- BN affine coefficients ---------------------------------------
__global__ void bncoeff(const float* __restrict__ sums,
                        const float* __restrict__ gamma,
                        const float* __restrict__ beta,
                        float* __restrict__ coeff) {
  int c = threadIdx.x;  // 128 threads
  const float inv = 1.0f / (float)((size_t)Bn * Nn);
  float mean = sums[c] * inv;
  float var = sums[128 + c] * inv - mean * mean;
  float a = gamma[c] * rsqrtf(var + 1e-5f);
  coeff[c] = a;
  coeff[128 + c] = beta[c] - mean * a;
}

// ---------------- fused weighted conv (per-tap GEMM + shift-combine) -----------
// Xin:  [B][N][128] f16 curve-order rows (TRANS=1: raw y1, bn+relu applied here)
// W:    [9][128][128] f16   G: [B][9][N] f32
// Yout: [B][N][128] f16     sums: [2][128] f32 (atomic)
template <int TRANS>
__global__ __launch_bounds__(256, 2) void conv_mfma(
    const _Float16* __restrict__ Xin, const _Float16* __restrict__ W,
    const float* __restrict__ G, _Float16* __restrict__ Yout,
    float* __restrict__ sums, const float* __restrict__ coeff) {
  __shared__ __align__(16) _Float16 Xs[T_HALO * XROW];  // 17408 B
  __shared__ float Ys[128 * YSTR];                      // 35328 B
  __shared__ float red[256];

  const int tid = threadIdx.x;
  const int b = blockIdx.x / TILES_PB;
  const int tile = blockIdx.x % TILES_PB;
  const int p0 = tile * T_OUT;
  const int valid = imin(T_OUT, Nn - p0);
  const int ch = tid & 15;

  float ca[8], cb[8];
  if (TRANS) {
#pragma unroll
    for (int i = 0; i < 8; ++i) {
      ca[i] = coeff[ch * 8 + i];
      cb[i] = coeff[128 + ch * 8 + i];
    }
  }
  // ---- stage X tile (halo rows r=0..63 <-> q = p0-4+r), zero OOB ----
#pragma unroll
  for (int pass = 0; pass < 4; ++pass) {
    int r = pass * 16 + (tid >> 4);
    int q = p0 - 4 + r;
    f16x8 v = {0, 0, 0, 0, 0, 0, 0, 0};
    if (q >= 0 && q < Nn) {
      v = *(const f16x8*)(Xin + ((size_t)b * Nn + q) * Cn + ch * 8);
      if (TRANS) {
#pragma unroll
        for (int i = 0; i < 8; ++i) {
          float f = fmaxf(ca[i] * (float)v[i] + cb[i], 0.f);
          v[i] = (_Float16)f;
        }
      }
    }
    *(f16x8*)(&Xs[r * XROW + ch * 8]) = v;
  }

  const int w = tid >> 6;
  const int lane = tid & 63;
  const int l15 = lane & 15;
  const int quad = lane >> 4;
  const int og = tid & 127;            // combine: this thread's out channel
  const int pbase = (tid >> 7) * 28;   // combine: position range start
  const int jmax = imin(28, valid - pbase);

  float out_acc[28];
#pragma unroll
  for (int j = 0; j < 28; ++j) out_acc[j] = 0.f;

  const float* gb = G + (size_t)b * KT * Nn;
  __syncthreads();

#pragma unroll 1
  for (int t = 0; t < KT; ++t) {
    // y_t = W_t @ X  (M=128, N=64 halo, K=128); wave w owns rows 32w..32w+31
    f32x4 acc[2][4];
    const f32x4 z4 = {0.f, 0.f, 0.f, 0.f};
#pragma unroll
    for (int mt = 0; mt < 2; ++mt)
#pragma unroll
      for (int nt = 0; nt < 4; ++nt) acc[mt][nt] = z4;

    const _Float16* Wt = W + (size_t)t * Cn * Cn + (w * 32) * Cn;
#pragma unroll
    for (int ko = 0; ko < 4; ++ko) {
      f16x8 a0 = *(const f16x8*)(Wt + l15 * Cn + ko * 32 + quad * 8);
      f16x8 a1 = *(const f16x8*)(Wt + (16 + l15) * Cn + ko * 32 + quad * 8);
#pragma unroll
      for (int nt = 0; nt < 4; ++nt) {
        f16x8 bv = *(const f16x8*)(&Xs[(nt * 16 + l15) * XROW + ko * 32 + quad * 8]);
        acc[0][nt] = __builtin_amdgcn_mfma_f32_16x16x32_f16(a0, bv, acc[0][nt], 0, 0, 0);
        acc[1][nt] = __builtin_amdgcn_mfma_f32_16x16x32_f16(a1, bv, acc[1][nt], 0, 0, 0);
      }
    }
    __syncthreads();  // protect Ys readers of previous tap
    // C/D layout: col = lane&15 (position), row = quad*4+reg (channel)
#pragma unroll
    for (int mt = 0; mt < 2; ++mt)
#pragma unroll
      for (int nt = 0; nt < 4; ++nt)
#pragma unroll
        for (int rg = 0; rg < 4; ++rg)
          Ys[(w * 32 + mt * 16 + quad * 4 + rg) * YSTR + nt * 16 + l15] = acc[mt][nt][rg];
    __syncthreads();

    // combine: out[o,p] += g[p,t] * y[o, p+t] (halo index = p_local + t)
    const float* gt = gb + (size_t)t * Nn + p0 + pbase;
    const float* yrow = &Ys[og * YSTR + pbase + t];
#pragma unroll
    for (int j = 0; j < 28; ++j) {
      if (j < jmax) out_acc[j] += gt[j] * yrow[j];
    }
  }

  // ---- epilogue: BN sums + f16 store via LDS (reuse Xs as [p][XROW]) ----
  float s = 0.f, s2 = 0.f;
  _Float16* Os = Xs;
#pragma unroll
  for (int j = 0; j < 28; ++j) {
    if (j < jmax) {
      float v = out_acc[j];
      s += v;
      s2 += v * v;
      Os[(pbase + j) * XROW + og] = (_Float16)v;
    }
  }
  red[tid] = 0.f;
  __syncthreads();
  atomicAdd(&red[og], s);
  atomicAdd(&red[128 + og], s2);
#pragma unroll
  for (int pass = 0; pass < 4; ++pass) {
    int r = pass * 16 + (tid >> 4);
    if (r < valid) {
      f16x8 v = *(const f16x8*)(&Os[r * XROW + ch * 8]);
      *(f16x8*)(Yout + ((size_t)b * Nn + p0 + r) * Cn + ch * 8) = v;
    }
  }
  __syncthreads();
  if (tid < 128) {
    atomicAdd(&sums[tid], red[tid]);
    atomicAdd(&sums[128 + tid], red[128 + tid]);
  }
}

// ---------------- final: scatter + BN2 affine + residual + relu ----------------
__global__ __launch_bounds__(256) void final_k(const _Float16* __restrict__ y2,
                                               const float* __restrict__ x,
                                               const int* __restrict__ reidx,
                                               const float* __restrict__ coeff,
                                               float* __restrict__ out) {
  __shared__ __align__(16) _Float16 tile[T_HALO * XROW];
  __shared__ float Ac[128], Bc[128];
  int tid = threadIdx.x;
  int b = blockIdx.x >> 10;
  int n0 = (blockIdx.x & 1023) * 64;
  if (tid < 128) {
    Ac[tid] = coeff[tid];
    Bc[tid] = coeff[128 + tid];
  }
  int ch = tid & 15;
#pragma unroll
  for (int pass = 0; pass < 4; ++pass) {
    int r = pass * 16 + (tid >> 4);
    int m = reidx[(size_t)b * Nn + n0 + r];
    f16x8 v = *(const f16x8*)(y2 + ((size_t)b * Nn + m) * Cn + ch * 8);
    *(f16x8*)(&tile[r * XROW + ch * 8]) = v;
  }
  __syncthreads();
  int j = tid & 63;
  int cw = tid >> 6;
  for (int ci = 0; ci < 32; ++ci) {
    int c = ci * 4 + cw;
    float v = (float)tile[j * XROW + c];
    size_t gi = ((size_t)b * Cn + c) * Nn + n0 + j;
    float r = Ac[c] * v + Bc[c] + x[gi];
    out[gi] = fmaxf(r, 0.f);
  }
}

extern "C" void kernel_launch(void* const* d_in, const int* in_sizes, int n_in,
                              void* d_out, int out_size, void* d_ws, size_t ws_size,
                              hipStream_t stream) {
  (void)in_sizes; (void)n_in; (void)out_size; (void)ws_size;
  const float* x = (const float*)d_in[0];
  const float* coords = (const float*)d_in[1];
  const int* indices = (const int*)d_in[2];
  const int* reindices = (const int*)d_in[3];
  const float* w1 = (const float*)d_in[4];
  const float* gamma1 = (const float*)d_in[5];
  const float* beta1 = (const float*)d_in[6];
  const float* w2 = (const float*)d_in[7];
  const float* gamma2 = (const float*)d_in[8];
  const float* beta2 = (const float*)d_in[9];
  float* out = (float*)d_out;

  // workspace: [0,64MB) xp -> y2 ; then sums1/sums2/coeff1/coeff2 ; then Wr f16
  char* ws = (char*)d_ws;
  const size_t BUF0 = (size_t)Bn * Nn * Cn * sizeof(_Float16);  // 64 MB
  _Float16* buf0 = (_Float16*)ws;
  float* sums1 = (float*)(ws + BUF0);
  float* sums2 = sums1 + 256;
  float* coeff1 = sums1 + 512;
  float* coeff2 = sums1 + 768;
  _Float16* Wr = (_Float16*)(ws + BUF0 + 4096);  // 2*9*128*128 f16 = 576 KB

  // d_out doubles as scratch until the final kernel: y1 f16 [0,64MB), cp, G
  char* dob = (char*)d_out;
  _Float16* y1 = (_Float16*)dob;
  float* cp = (float*)(dob + BUF0);                               // 3 MB
  float* G = (float*)(dob + BUF0 + (size_t)Bn * 3 * Nn * 4);      // 9 MB

  hipMemsetAsync(sums1, 0, 512 * sizeof(float), stream);

  repack_w<<<1152, 256, 0, stream>>>(w1, w2, Wr);
  gather_x<<<Bn * 1024, 256, 0, stream>>>(x, reindices, buf0);
  gather_cp<<<1024, 256, 0, stream>>>(coords, indices, cp);
  compute_g<<<1024, 256, 0, stream>>>(cp, G);

  conv_mfma<0><<<Bn * TILES_PB, 256, 0, stream>>>(buf0, Wr, G, y1, sums1, nullptr);
  bncoeff<<<1, 128, 0, stream>>>(sums1, gamma1, beta1, coeff1);
  conv_mfma<1><<<Bn * TILES_PB, 256, 0, stream>>>(y1, Wr + (size_t)KT * Cn * Cn, G,
                                                  buf0, sums2, coeff1);
  bncoeff<<<1, 128, 0, stream>>>(sums2, gamma2, beta2, coeff2);
  final_k<<<Bn * 1024, 256, 0, stream>>>(buf0, x, reindices, coeff2, out);
}

// Round 2
// 964.048 us; speedup vs baseline: 1.0431x; 1.0431x over previous
//
#include <hip/hip_runtime.h>

#define Bn 4
#define Cn 128
#define Nn 65536
#define KT 9
#define T_OUT 64
#define T_HALO 72
#define TILES_PB 1024   // 65536/64
#define XROW 136        // f16 elems per LDS X row (128 + 8 pad) = 272 B

typedef _Float16 f16x8 __attribute__((ext_vector_type(8)));
typedef _Float16 f16x4 __attribute__((ext_vector_type(4)));
typedef float f32x4 __attribute__((ext_vector_type(4)));

// ---------------- repack weights: [O][C][K] f32 -> [t][o][c] f16 ----------------
__global__ __launch_bounds__(256) void repack_w(const float* __restrict__ w1,
                                                const float* __restrict__ w2,
                                                _Float16* __restrict__ Wr) {
  int i = blockIdx.x * 256 + threadIdx.x;  // [cv][t][o][c], total 2*9*128*128
  int c = i & 127;
  int o = (i >> 7) & 127;
  int t = (i >> 14) % KT;
  int cv = i / (KT << 14);
  const float* w = cv ? w2 : w1;
  Wr[i] = (_Float16)w[(o * 128 + c) * KT + t];
}

// ---------------- gather x into curve order, f16, channel-contiguous rows ------
__global__ __launch_bounds__(256) void gather_x(const float* __restrict__ x,
                                                const int* __restrict__ reidx,
                                                _Float16* __restrict__ xp) {
  __shared__ __align__(16) _Float16 tile[64 * XROW];
  int tid = threadIdx.x;
  int b = blockIdx.x >> 10;
  int n0 = (blockIdx.x & 1023) * 64;
  int j = tid & 63;
  int cw = tid >> 6;
  const float* xb = x + (size_t)b * Cn * Nn;
  for (int ci = 0; ci < 32; ++ci) {
    int c = ci * 4 + cw;
    float v = xb[(size_t)c * Nn + n0 + j];      // coalesced over j
    tile[j * XROW + c] = (_Float16)v;           // LDS transpose
  }
  __syncthreads();
  int ch = tid & 15;
#pragma unroll
  for (int pass = 0; pass < 4; ++pass) {
    int r = pass * 16 + (tid >> 4);
    int m = reidx[(size_t)b * Nn + n0 + r];
    f16x8 v = *(const f16x8*)(&tile[r * XROW + ch * 8]);
    *(f16x8*)(xp + ((size_t)b * Nn + m) * Cn + ch * 8) = v;  // 256B row scatter
  }
}

// ---------------- gather coords into curve order (planar) ----------------------
__global__ __launch_bounds__(256) void gather_cp(const float* __restrict__ coords,
                                                 const int* __restrict__ indices,
                                                 float* __restrict__ cp) {
  int gidx = blockIdx.x * 256 + threadIdx.x;  // b*N + m
  int b = gidx >> 16;
  int m = gidx & (Nn - 1);
  int idx = indices[gidx];
  const float* cb = coords + (size_t)b * 3 * Nn;
  float* cpb = cp + (size_t)b * 3 * Nn;
  cpb[m] = cb[idx];
  cpb[Nn + m] = cb[Nn + idx];
  cpb[2 * Nn + m] = cb[2 * Nn + idx];
}

// ---------------- gaussian tap weights g[b][t][m] ------------------------------
__global__ __launch_bounds__(256) void compute_g(const float* __restrict__ cp,
                                                 float* __restrict__ G) {
  int gidx = blockIdx.x * 256 + threadIdx.x;
  int b = gidx >> 16;
  int m = gidx & (Nn - 1);
  const float* cpb = cp + (size_t)b * 3 * Nn;
  float x0 = cpb[m], y0 = cpb[Nn + m], z0 = cpb[2 * Nn + m];
  float* Gb = G + (size_t)b * KT * Nn;
#pragma unroll
  for (int t = 0; t < KT; ++t) {
    int q = m + t - 4;
    q = q < 0 ? 0 : (q > Nn - 1 ? Nn - 1 : q);  // OOB value irrelevant (x==0 there)
    float dx = cpb[q] - x0;
    float dy = cpb[Nn + q] - y0;
    float dz = cpb[2 * Nn + q] - z0;
    Gb[(size_t)t * Nn + m] = __expf(-(dx * dx + dy * dy + dz * dz));  // sigma=1
  }
}

// ---------------- BN affine coefficients ---------------------------------------
__global__ void bncoeff(const float* __restrict__ sums,
                        const float* __restrict__ gamma,
                        const float* __restrict__ beta,
                        float* __restrict__ coeff) {
  int c = threadIdx.x;  // 128 threads
  const float inv = 1.0f / (float)((size_t)Bn * Nn);
  float mean = sums[c] * inv;
  float var = sums[128 + c] * inv - mean * mean;
  float a = gamma[c] * rsqrtf(var + 1e-5f);
  coeff[c] = a;
  coeff[128 + c] = beta[c] - mean * a;
}

__device__ __forceinline__ f16x8 scale8(f16x8 v, _Float16 g) {
  f16x8 r;
#pragma unroll
  for (int i = 0; i < 8; ++i) r[i] = v[i] * g;  // 4x v_pk_mul_f16
  return r;
}

// ---------------- fused weighted conv: tap-accumulating MFMA -------------------
// out[o,p] = sum_t W_t[o,:] . ( x[:, p+t-4] * g[p,t] )  -- g folded into B-frag,
// all taps accumulate in the same C registers. Waves tile 2(M)x2(N).
// Xin:  [B][N][128] f16 curve-order rows (TRANS=1: raw y1, bn1+relu applied here)
// W:    [9][128][128] f16   G: [B][9][N] f32
// Yout: [B][N][128] f16     sums: [2][128] f32 (atomic)
template <int TRANS>
__global__ __launch_bounds__(256) void conv_mfma(
    const _Float16* __restrict__ Xin, const _Float16* __restrict__ W,
    const float* __restrict__ G, _Float16* __restrict__ Yout,
    float* __restrict__ sums, const float* __restrict__ coeff) {
  __shared__ __align__(16) _Float16 Xs[T_HALO * XROW];  // 19584 B
  __shared__ float red[256];

  const int tid = threadIdx.x;
  const int b = blockIdx.x >> 10;
  const int p0 = (blockIdx.x & 1023) * T_OUT;
  const int ch = tid & 15;

  float ca[8], cb[8];
  if (TRANS) {
#pragma unroll
    for (int i = 0; i < 8; ++i) {
      ca[i] = coeff[ch * 8 + i];
      cb[i] = coeff[128 + ch * 8 + i];
    }
  }
  // ---- stage X halo tile (rows r=0..71 <-> q = p0-4+r), zero OOB ----
#pragma unroll
  for (int pass = 0; pass < 5; ++pass) {
    int r = pass * 16 + (tid >> 4);
    if (r < T_HALO) {
      int q = p0 - 4 + r;
      f16x8 v = {0, 0, 0, 0, 0, 0, 0, 0};
      if (q >= 0 && q < Nn) {
        v = *(const f16x8*)(Xin + ((size_t)b * Nn + q) * Cn + ch * 8);
        if (TRANS) {
#pragma unroll
          for (int i = 0; i < 8; ++i) {
            float f = fmaxf(ca[i] * (float)v[i] + cb[i], 0.f);
            v[i] = (_Float16)f;
          }
        }
      }
      *(f16x8*)(&Xs[r * XROW + ch * 8]) = v;
    }
  }

  const int w = tid >> 6;
  const int lane = tid & 63;
  const int l15 = lane & 15;
  const int quad = lane >> 4;
  const int wm = w >> 1;   // M-stripe: channels wm*64 .. wm*64+63
  const int wn = w & 1;    // N-stripe: positions wn*32 .. wn*32+31

  // preload per-lane gaussian taps for this lane's two position columns
  _Float16 gh[KT][2];
  {
    const float* gb = G + (size_t)b * KT * Nn + p0 + wn * 32 + l15;
#pragma unroll
    for (int t = 0; t < KT; ++t) {
#pragma unroll
      for (int nt = 0; nt < 2; ++nt)
        gh[t][nt] = (_Float16)gb[(size_t)t * Nn + nt * 16];
    }
  }

  f32x4 acc[4][2];
  const f32x4 z4 = {0.f, 0.f, 0.f, 0.f};
#pragma unroll
  for (int mt = 0; mt < 4; ++mt)
#pragma unroll
    for (int nt = 0; nt < 2; ++nt) acc[mt][nt] = z4;

  __syncthreads();

#pragma unroll 1
  for (int t = 0; t < KT; ++t) {
    const _Float16* Wt = W + ((size_t)t << 14) + (wm * 64) * Cn;
#pragma unroll
    for (int ko = 0; ko < 4; ++ko) {
      f16x8 a[4];
#pragma unroll
      for (int mt = 0; mt < 4; ++mt)
        a[mt] = *(const f16x8*)(Wt + (mt * 16 + l15) * Cn + ko * 32 + quad * 8);
#pragma unroll
      for (int nt = 0; nt < 2; ++nt) {
        f16x8 bv = *(const f16x8*)(&Xs[(wn * 32 + nt * 16 + l15 + t) * XROW + ko * 32 + quad * 8]);
        bv = scale8(bv, gh[t][nt]);
#pragma unroll
        for (int mt = 0; mt < 4; ++mt)
          acc[mt][nt] = __builtin_amdgcn_mfma_f32_16x16x32_f16(a[mt], bv, acc[mt][nt], 0, 0, 0);
      }
    }
  }

  // ---- epilogue: transpose via LDS (reuse Xs as Os[p][XROW]) + BN sums ----
  __syncthreads();  // all taps done reading Xs
  _Float16* Os = Xs;
  // C/D layout: col(position) = l15, row(channel) = quad*4+rg
#pragma unroll
  for (int mt = 0; mt < 4; ++mt)
#pragma unroll
    for (int nt = 0; nt < 2; ++nt) {
      f16x4 o4;
#pragma unroll
      for (int rg = 0; rg < 4; ++rg) o4[rg] = (_Float16)acc[mt][nt][rg];
      *(f16x4*)(&Os[(wn * 32 + nt * 16 + l15) * XROW + wm * 64 + mt * 16 + quad * 4]) = o4;
    }
  red[tid] = 0.f;
  __syncthreads();

  const int og = tid & 127;
  const int pb = (tid >> 7) * 32;
  float s = 0.f, s2 = 0.f;
#pragma unroll
  for (int j = 0; j < 32; ++j) {
    float v = (float)Os[(pb + j) * XROW + og];
    s += v;
    s2 += v * v;
  }
  atomicAdd(&red[og], s);
  atomicAdd(&red[128 + og], s2);

#pragma unroll
  for (int pass = 0; pass < 4; ++pass) {
    int r = pass * 16 + (tid >> 4);
    f16x8 v = *(const f16x8*)(&Os[r * XROW + ch * 8]);
    *(f16x8*)(Yout + ((size_t)b * Nn + p0 + r) * Cn + ch * 8) = v;
  }
  __syncthreads();
  if (tid < 128) {
    atomicAdd(&sums[tid], red[tid]);
    atomicAdd(&sums[128 + tid], red[128 + tid]);
  }
}

// ---------------- final: scatter + BN2 affine + residual + relu ----------------
__global__ __launch_bounds__(256) void final_k(const _Float16* __restrict__ y2,
                                               const float* __restrict__ x,
                                               const int* __restrict__ reidx,
                                               const float* __restrict__ coeff,
                                               float* __restrict__ out) {
  __shared__ __align__(16) _Float16 tile[64 * XROW];
  __shared__ float Ac[128], Bc[128];
  int tid = threadIdx.x;
  int b = blockIdx.x >> 10;
  int n0 = (blockIdx.x & 1023) * 64;
  if (tid < 128) {
    Ac[tid] = coeff[tid];
    Bc[tid] = coeff[128 + tid];
  }
  int ch = tid & 15;
#pragma unroll
  for (int pass = 0; pass < 4; ++pass) {
    int r = pass * 16 + (tid >> 4);
    int m = reidx[(size_t)b * Nn + n0 + r];
    f16x8 v = *(const f16x8*)(y2 + ((size_t)b * Nn + m) * Cn + ch * 8);
    *(f16x8*)(&tile[r * XROW + ch * 8]) = v;
  }
  __syncthreads();
  int j = tid & 63;
  int cw = tid >> 6;
  for (int ci = 0; ci < 32; ++ci) {
    int c = ci * 4 + cw;
    float v = (float)tile[j * XROW + c];
    size_t gi = ((size_t)b * Cn + c) * Nn + n0 + j;
    float r = Ac[c] * v + Bc[c] + x[gi];
    out[gi] = fmaxf(r, 0.f);
  }
}

extern "C" void kernel_launch(void* const* d_in, const int* in_sizes, int n_in,
                              void* d_out, int out_size, void* d_ws, size_t ws_size,
                              hipStream_t stream) {
  (void)in_sizes; (void)n_in; (void)out_size; (void)ws_size;
  const float* x = (const float*)d_in[0];
  const float* coords = (const float*)d_in[1];
  const int* indices = (const int*)d_in[2];
  const int* reindices = (const int*)d_in[3];
  const float* w1 = (const float*)d_in[4];
  const float* gamma1 = (const float*)d_in[5];
  const float* beta1 = (const float*)d_in[6];
  const float* w2 = (const float*)d_in[7];
  const float* gamma2 = (const float*)d_in[8];
  const float* beta2 = (const float*)d_in[9];
  float* out = (float*)d_out;

  // workspace: [0,64MB) xp -> y2 ; then sums1/sums2/coeff1/coeff2 ; then Wr f16
  char* ws = (char*)d_ws;
  const size_t BUF0 = (size_t)Bn * Nn * Cn * sizeof(_Float16);  // 64 MB
  _Float16* buf0 = (_Float16*)ws;
  float* sums1 = (float*)(ws + BUF0);
  float* sums2 = sums1 + 256;
  float* coeff1 = sums1 + 512;
  float* coeff2 = sums1 + 768;
  _Float16* Wr = (_Float16*)(ws + BUF0 + 4096);  // 2*9*128*128 f16 = 576 KB

  // d_out doubles as scratch until the final kernel: y1 f16 [0,64MB), cp, G
  char* dob = (char*)d_out;
  _Float16* y1 = (_Float16*)dob;
  float* cp = (float*)(dob + BUF0);                               // 3 MB
  float* G = (float*)(dob + BUF0 + (size_t)Bn * 3 * Nn * 4);      // 9 MB

  hipMemsetAsync(sums1, 0, 512 * sizeof(float), stream);

  repack_w<<<1152, 256, 0, stream>>>(w1, w2, Wr);
  gather_x<<<Bn * 1024, 256, 0, stream>>>(x, reindices, buf0);
  gather_cp<<<1024, 256, 0, stream>>>(coords, indices, cp);
  compute_g<<<1024, 256, 0, stream>>>(cp, G);

  conv_mfma<0><<<Bn * TILES_PB, 256, 0, stream>>>(buf0, Wr, G, y1, sums1, nullptr);
  bncoeff<<<1, 128, 0, stream>>>(sums1, gamma1, beta1, coeff1);
  conv_mfma<1><<<Bn * TILES_PB, 256, 0, stream>>>(y1, Wr + (size_t)KT * Cn * Cn, G,
                                                  buf0, sums2, coeff1);
  bncoeff<<<1, 128, 0, stream>>>(sums2, gamma2, beta2, coeff2);
  final_k<<<Bn * 1024, 256, 0, stream>>>(buf0, x, reindices, coeff2, out);
}

// Round 3
// 581.253 us; speedup vs baseline: 1.7300x; 1.6586x over previous
//
#include <hip/hip_runtime.h>

#define Bn 4
#define Cn 128
#define Nn 65536
#define KT 9
#define T_OUT 256
#define T_HALO 264
#define XROW 136        // f16 elems per LDS X row (128 + 8 pad) = 272 B
#define GROW 264        // f16 elems per LDS G row

typedef _Float16 f16x8 __attribute__((ext_vector_type(8)));
typedef _Float16 f16x4 __attribute__((ext_vector_type(4)));
typedef float f32x4 __attribute__((ext_vector_type(4)));

// ---------------- repack weights: [O][C][K] f32 -> [t][o][c] f16 ----------------
__global__ __launch_bounds__(256) void repack_w(const float* __restrict__ w1,
                                                const float* __restrict__ w2,
                                                _Float16* __restrict__ Wr) {
  int i = blockIdx.x * 256 + threadIdx.x;  // [cv][t][o][c], total 2*9*128*128
  int c = i & 127;
  int o = (i >> 7) & 127;
  int t = (i >> 14) % KT;
  int cv = i / (KT << 14);
  const float* w = cv ? w2 : w1;
  Wr[i] = (_Float16)w[(o * 128 + c) * KT + t];
}

// ---------------- gather x into curve order, f16, channel-contiguous rows ------
__global__ __launch_bounds__(256) void gather_x(const float* __restrict__ x,
                                                const int* __restrict__ reidx,
                                                _Float16* __restrict__ xp) {
  __shared__ __align__(16) _Float16 tile[64 * XROW];
  int tid = threadIdx.x;
  int b = blockIdx.x >> 10;
  int n0 = (blockIdx.x & 1023) * 64;
  int j = tid & 63;
  int cw = tid >> 6;
  const float* xb = x + (size_t)b * Cn * Nn;
  for (int ci = 0; ci < 32; ++ci) {
    int c = ci * 4 + cw;
    float v = xb[(size_t)c * Nn + n0 + j];      // coalesced over j
    tile[j * XROW + c] = (_Float16)v;           // LDS transpose
  }
  __syncthreads();
  int ch = tid & 15;
#pragma unroll
  for (int pass = 0; pass < 4; ++pass) {
    int r = pass * 16 + (tid >> 4);
    int m = reidx[(size_t)b * Nn + n0 + r];
    f16x8 v = *(const f16x8*)(&tile[r * XROW + ch * 8]);
    *(f16x8*)(xp + ((size_t)b * Nn + m) * Cn + ch * 8) = v;  // 256B row scatter
  }
}

// ---------------- gather coords into curve order (planar) ----------------------
__global__ __launch_bounds__(256) void gather_cp(const float* __restrict__ coords,
                                                 const int* __restrict__ indices,
                                                 float* __restrict__ cp) {
  int gidx = blockIdx.x * 256 + threadIdx.x;  // b*N + m
  int b = gidx >> 16;
  int m = gidx & (Nn - 1);
  int idx = indices[gidx];
  const float* cb = coords + (size_t)b * 3 * Nn;
  float* cpb = cp + (size_t)b * 3 * Nn;
  cpb[m] = cb[idx];
  cpb[Nn + m] = cb[Nn + idx];
  cpb[2 * Nn + m] = cb[2 * Nn + idx];
}

// ---------------- gaussian tap weights g[b][t][m] ------------------------------
__global__ __launch_bounds__(256) void compute_g(const float* __restrict__ cp,
                                                 float* __restrict__ G) {
  int gidx = blockIdx.x * 256 + threadIdx.x;
  int b = gidx >> 16;
  int m = gidx & (Nn - 1);
  const float* cpb = cp + (size_t)b * 3 * Nn;
  float x0 = cpb[m], y0 = cpb[Nn + m], z0 = cpb[2 * Nn + m];
  float* Gb = G + (size_t)b * KT * Nn;
#pragma unroll
  for (int t = 0; t < KT; ++t) {
    int q = m + t - 4;
    q = q < 0 ? 0 : (q > Nn - 1 ? Nn - 1 : q);  // OOB value irrelevant (x==0 there)
    float dx = cpb[q] - x0;
    float dy = cpb[Nn + q] - y0;
    float dz = cpb[2 * Nn + q] - z0;
    Gb[(size_t)t * Nn + m] = __expf(-(dx * dx + dy * dy + dz * dz));  // sigma=1
  }
}

// ---------------- BN affine coefficients ---------------------------------------
__global__ void bncoeff(const float* __restrict__ sums,
                        const float* __restrict__ gamma,
                        const float* __restrict__ beta,
                        float* __restrict__ coeff) {
  int c = threadIdx.x;  // 128 threads
  const float inv = 1.0f / (float)((size_t)Bn * Nn);
  float mean = sums[c] * inv;
  float var = sums[128 + c] * inv - mean * mean;
  float a = gamma[c] * rsqrtf(var + 1e-5f);
  coeff[c] = a;
  coeff[128 + c] = beta[c] - mean * a;
}

__device__ __forceinline__ f16x8 scale8(f16x8 v, _Float16 g) {
  f16x8 r;
#pragma unroll
  for (int i = 0; i < 8; ++i) r[i] = v[i] * g;  // 4x v_pk_mul_f16
  return r;
}

// ---------------- fused weighted conv: tap-accumulating MFMA -------------------
// out[o,p] = sum_t W_t[o,:] . ( x[:, p+t-4] * g[p,t] )  -- g folded into B-frag,
// all taps accumulate in the same C registers. Waves tile 2(M)x2(N); per-wave
// register tile M64 x N128 (A-frag reuse 8x) to amortize global W reads.
// Xin:  [B][N][128] f16 curve-order rows (TRANS=1: raw y1, bn1+relu applied here)
// W:    [9][128][128] f16   G: [B][9][N] f32
// Yout: [B][N][128] f16     sums: [2][128] f32 (atomic)
template <int TRANS>
__global__ __launch_bounds__(256) void conv_mfma(
    const _Float16* __restrict__ Xin, const _Float16* __restrict__ W,
    const float* __restrict__ G, _Float16* __restrict__ Yout,
    float* __restrict__ sums, const float* __restrict__ coeff) {
  __shared__ __align__(16) _Float16 Xs[T_HALO * XROW];  // 71808 B
  __shared__ __align__(4) _Float16 Gs[KT * GROW];       // 4752 B
  __shared__ float red[512];                            // 2048 B

  const int tid = threadIdx.x;
  const int b = blockIdx.x >> 8;
  const int p0 = (blockIdx.x & 255) * T_OUT;
  const int ch = tid & 15;

  float ca[8], cb[8];
  if (TRANS) {
#pragma unroll
    for (int i = 0; i < 8; ++i) {
      ca[i] = coeff[ch * 8 + i];
      cb[i] = coeff[128 + ch * 8 + i];
    }
  }
  // ---- stage X halo tile (rows r=0..263 <-> q = p0-4+r), zero OOB ----
#pragma unroll
  for (int pass = 0; pass < 17; ++pass) {
    int r = pass * 16 + (tid >> 4);
    if (r < T_HALO) {
      int q = p0 - 4 + r;
      f16x8 v = {0, 0, 0, 0, 0, 0, 0, 0};
      if (q >= 0 && q < Nn) {
        v = *(const f16x8*)(Xin + ((size_t)b * Nn + q) * Cn + ch * 8);
        if (TRANS) {
#pragma unroll
          for (int i = 0; i < 8; ++i) {
            float f = fmaxf(ca[i] * (float)v[i] + cb[i], 0.f);
            v[i] = (_Float16)f;
          }
        }
      }
      *(f16x8*)(&Xs[r * XROW + ch * 8]) = v;
    }
  }
  // ---- stage G tile as f16 ----
  {
    const float* gb = G + (size_t)b * KT * Nn + p0;
    for (int i = tid; i < KT * 256; i += 256) {
      int t = i >> 8;
      int p = i & 255;
      Gs[t * GROW + p] = (_Float16)gb[(size_t)t * Nn + p];
    }
  }

  const int w = tid >> 6;
  const int lane = tid & 63;
  const int l15 = lane & 15;
  const int quad = lane >> 4;
  const int wm = w >> 1;   // M-stripe: channels wm*64 .. wm*64+63
  const int wn = w & 1;    // N-stripe: positions wn*128 .. wn*128+127

  f32x4 acc[4][8];
  const f32x4 z4 = {0.f, 0.f, 0.f, 0.f};
#pragma unroll
  for (int mt = 0; mt < 4; ++mt)
#pragma unroll
    for (int nt = 0; nt < 8; ++nt) acc[mt][nt] = z4;

  __syncthreads();

#pragma unroll 1
  for (int t = 0; t < KT; ++t) {
    // per-tap gaussian scalars for this lane's 8 position columns
    _Float16 gt[8];
#pragma unroll
    for (int nt = 0; nt < 8; ++nt)
      gt[nt] = Gs[t * GROW + wn * 128 + nt * 16 + l15];

    const _Float16* Wt = W + ((size_t)t << 14) + (wm * 64) * Cn;
#pragma unroll
    for (int ko = 0; ko < 4; ++ko) {
      f16x8 a[4];
#pragma unroll
      for (int mt = 0; mt < 4; ++mt)
        a[mt] = *(const f16x8*)(Wt + (mt * 16 + l15) * Cn + ko * 32 + quad * 8);
#pragma unroll
      for (int nt = 0; nt < 8; ++nt) {
        f16x8 bv = *(const f16x8*)(&Xs[(wn * 128 + nt * 16 + l15 + t) * XROW + ko * 32 + quad * 8]);
        bv = scale8(bv, gt[nt]);
#pragma unroll
        for (int mt = 0; mt < 4; ++mt)
          acc[mt][nt] = __builtin_amdgcn_mfma_f32_16x16x32_f16(a[mt], bv, acc[mt][nt], 0, 0, 0);
      }
    }
  }

  // ---- BN partial sums from f32 accumulators (shfl tree over l15) ----
  // channel of acc[mt][*][rg] = wm*64 + mt*16 + quad*4 + rg
  f32x4 s4[4], q4[4];
#pragma unroll
  for (int mt = 0; mt < 4; ++mt) {
#pragma unroll
    for (int rg = 0; rg < 4; ++rg) {
      float s = 0.f, q = 0.f;
#pragma unroll
      for (int nt = 0; nt < 8; ++nt) {
        float v = acc[mt][nt][rg];
        s += v;
        q += v * v;
      }
#pragma unroll
      for (int m = 1; m < 16; m <<= 1) {
        s += __shfl_xor(s, m);
        q += __shfl_xor(q, m);
      }
      s4[mt][rg] = s;
      q4[mt][rg] = q;
    }
  }
  __syncthreads();  // all waves done reading Xs; red free to write
  if (l15 == 0) {
#pragma unroll
    for (int mt = 0; mt < 4; ++mt) {
      int cbase = wm * 64 + mt * 16 + quad * 4;
      *(f32x4*)(&red[wn * 128 + cbase]) = s4[mt];
      *(f32x4*)(&red[256 + wn * 128 + cbase]) = q4[mt];
    }
  }

  // ---- epilogue: transpose via LDS (reuse Xs as Os[p][XROW]) ----
  _Float16* Os = Xs;
  // C/D layout: col(position) = l15, row(channel) = quad*4+rg
#pragma unroll
  for (int mt = 0; mt < 4; ++mt)
#pragma unroll
    for (int nt = 0; nt < 8; ++nt) {
      f16x4 o4;
#pragma unroll
      for (int rg = 0; rg < 4; ++rg) o4[rg] = (_Float16)acc[mt][nt][rg];
      *(f16x4*)(&Os[(wn * 128 + nt * 16 + l15) * XROW + wm * 64 + mt * 16 + quad * 4]) = o4;
    }
  __syncthreads();

  if (tid < 128) {
    atomicAdd(&sums[tid], red[tid] + red[128 + tid]);
    atomicAdd(&sums[128 + tid], red[256 + tid] + red[384 + tid]);
  }
#pragma unroll
  for (int pass = 0; pass < 16; ++pass) {
    int r = pass * 16 + (tid >> 4);
    f16x8 v = *(const f16x8*)(&Os[r * XROW + ch * 8]);
    *(f16x8*)(Yout + ((size_t)b * Nn + p0 + r) * Cn + ch * 8) = v;
  }
}

// ---------------- final: scatter + BN2 affine + residual + relu ----------------
__global__ __launch_bounds__(256) void final_k(const _Float16* __restrict__ y2,
                                               const float* __restrict__ x,
                                               const int* __restrict__ reidx,
                                               const float* __restrict__ coeff,
                                               float* __restrict__ out) {
  __shared__ __align__(16) _Float16 tile[64 * XROW];
  __shared__ float Ac[128], Bc[128];
  int tid = threadIdx.x;
  int b = blockIdx.x >> 10;
  int n0 = (blockIdx.x & 1023) * 64;
  if (tid < 128) {
    Ac[tid] = coeff[tid];
    Bc[tid] = coeff[128 + tid];
  }
  int ch = tid & 15;
#pragma unroll
  for (int pass = 0; pass < 4; ++pass) {
    int r = pass * 16 + (tid >> 4);
    int m = reidx[(size_t)b * Nn + n0 + r];
    f16x8 v = *(const f16x8*)(y2 + ((size_t)b * Nn + m) * Cn + ch * 8);
    *(f16x8*)(&tile[r * XROW + ch * 8]) = v;
  }
  __syncthreads();
  int j = tid & 63;
  int cw = tid >> 6;
  for (int ci = 0; ci < 32; ++ci) {
    int c = ci * 4 + cw;
    float v = (float)tile[j * XROW + c];
    size_t gi = ((size_t)b * Cn + c) * Nn + n0 + j;
    float r = Ac[c] * v + Bc[c] + x[gi];
    out[gi] = fmaxf(r, 0.f);
  }
}

extern "C" void kernel_launch(void* const* d_in, const int* in_sizes, int n_in,
                              void* d_out, int out_size, void* d_ws, size_t ws_size,
                              hipStream_t stream) {
  (void)in_sizes; (void)n_in; (void)out_size; (void)ws_size;
  const float* x = (const float*)d_in[0];
  const float* coords = (const float*)d_in[1];
  const int* indices = (const int*)d_in[2];
  const int* reindices = (const int*)d_in[3];
  const float* w1 = (const float*)d_in[4];
  const float* gamma1 = (const float*)d_in[5];
  const float* beta1 = (const float*)d_in[6];
  const float* w2 = (const float*)d_in[7];
  const float* gamma2 = (const float*)d_in[8];
  const float* beta2 = (const float*)d_in[9];
  float* out = (float*)d_out;

  // workspace: [0,64MB) xp -> y2 ; then sums1/sums2/coeff1/coeff2 ; then Wr f16
  char* ws = (char*)d_ws;
  const size_t BUF0 = (size_t)Bn * Nn * Cn * sizeof(_Float16);  // 64 MB
  _Float16* buf0 = (_Float16*)ws;
  float* sums1 = (float*)(ws + BUF0);
  float* sums2 = sums1 + 256;
  float* coeff1 = sums1 + 512;
  float* coeff2 = sums1 + 768;
  _Float16* Wr = (_Float16*)(ws + BUF0 + 4096);  // 2*9*128*128 f16 = 576 KB

  // d_out doubles as scratch until the final kernel: y1 f16 [0,64MB), cp, G
  char* dob = (char*)d_out;
  _Float16* y1 = (_Float16*)dob;
  float* cp = (float*)(dob + BUF0);                               // 3 MB
  float* G = (float*)(dob + BUF0 + (size_t)Bn * 3 * Nn * 4);      // 9 MB

  hipMemsetAsync(sums1, 0, 512 * sizeof(float), stream);

  repack_w<<<1152, 256, 0, stream>>>(w1, w2, Wr);
  gather_x<<<Bn * 1024, 256, 0, stream>>>(x, reindices, buf0);
  gather_cp<<<1024, 256, 0, stream>>>(coords, indices, cp);
  compute_g<<<1024, 256, 0, stream>>>(cp, G);

  conv_mfma<0><<<Bn * 256, 256, 0, stream>>>(buf0, Wr, G, y1, sums1, nullptr);
  bncoeff<<<1, 128, 0, stream>>>(sums1, gamma1, beta1, coeff1);
  conv_mfma<1><<<Bn * 256, 256, 0, stream>>>(y1, Wr + (size_t)KT * Cn * Cn, G,
                                             buf0, sums2, coeff1);
  bncoeff<<<1, 128, 0, stream>>>(sums2, gamma2, beta2, coeff2);
  final_k<<<Bn * 1024, 256, 0, stream>>>(buf0, x, reindices, coeff2, out);
}

// Round 4
// 562.247 us; speedup vs baseline: 1.7885x; 1.0338x over previous
//
#include <hip/hip_runtime.h>

#define Bn 4
#define Cn 128
#define Nn 65536
#define KT 9
#define T_OUT 256
#define T_HALO 264
#define XROW 136        // f16 elems per LDS X row (128 + 8 pad) = 272 B
#define GROW 264        // f16 elems per LDS G row
#define FT 66           // f32 transpose-tile row stride (dwords)

typedef _Float16 f16x8 __attribute__((ext_vector_type(8)));
typedef _Float16 f16x4 __attribute__((ext_vector_type(4)));
typedef float f32x4 __attribute__((ext_vector_type(4)));
typedef float f32x2 __attribute__((ext_vector_type(2)));

// ---------------- repack weights: [O][C][K] f32 -> [t][o][c] f16 ----------------
__global__ __launch_bounds__(256) void repack_w(const float* __restrict__ w1,
                                                const float* __restrict__ w2,
                                                _Float16* __restrict__ Wr) {
  int i = blockIdx.x * 256 + threadIdx.x;  // [cv][t][o][c], total 2*9*128*128
  int c = i & 127;
  int o = (i >> 7) & 127;
  int t = (i >> 14) % KT;
  int cv = i / (KT << 14);
  const float* w = cv ? w2 : w1;
  Wr[i] = (_Float16)w[(o * 128 + c) * KT + t];
}

// ---------------- gather x into curve order, f16, channel-contiguous rows ------
// stage1: coalesced float4 loads -> f32 LDS tile; stage2: transposed reads ->
// f16x8 row scatter (256B per row).
__global__ __launch_bounds__(256) void gather_x(const float* __restrict__ x,
                                                const int* __restrict__ reidx,
                                                _Float16* __restrict__ xp) {
  __shared__ float ft[128 * FT];  // 33792 B
  int tid = threadIdx.x;
  int b = blockIdx.x >> 10;
  int n0 = (blockIdx.x & 1023) * 64;
  const float* xb = x + (size_t)b * Cn * Nn;
  {
    int cc = tid >> 4;
    int j4 = (tid & 15) * 4;
#pragma unroll
    for (int pass = 0; pass < 8; ++pass) {
      int c = pass * 16 + cc;
      f32x4 v = *(const f32x4*)(&xb[(size_t)c * Nn + n0 + j4]);
      *(f32x2*)(&ft[c * FT + j4]) = f32x2{v.x, v.y};
      *(f32x2*)(&ft[c * FT + j4 + 2]) = f32x2{v.z, v.w};
    }
  }
  __syncthreads();
  int ch = tid & 15;
  int rr = tid >> 4;
#pragma unroll
  for (int pass = 0; pass < 4; ++pass) {
    int r = pass * 16 + rr;
    int m = reidx[(size_t)b * Nn + n0 + r];
    f16x8 v;
#pragma unroll
    for (int k = 0; k < 8; ++k) v[k] = (_Float16)ft[(ch * 8 + k) * FT + r];
    *(f16x8*)(xp + ((size_t)b * Nn + m) * Cn + ch * 8) = v;
  }
}

// ---------------- gather coords into curve order (planar) ----------------------
__global__ __launch_bounds__(256) void gather_cp(const float* __restrict__ coords,
                                                 const int* __restrict__ indices,
                                                 float* __restrict__ cp) {
  int gidx = blockIdx.x * 256 + threadIdx.x;  // b*N + m
  int b = gidx >> 16;
  int m = gidx & (Nn - 1);
  int idx = indices[gidx];
  const float* cb = coords + (size_t)b * 3 * Nn;
  float* cpb = cp + (size_t)b * 3 * Nn;
  cpb[m] = cb[idx];
  cpb[Nn + m] = cb[Nn + idx];
  cpb[2 * Nn + m] = cb[2 * Nn + idx];
}

// ---------------- gaussian tap weights g[b][t][m] ------------------------------
__global__ __launch_bounds__(256) void compute_g(const float* __restrict__ cp,
                                                 float* __restrict__ G) {
  int gidx = blockIdx.x * 256 + threadIdx.x;
  int b = gidx >> 16;
  int m = gidx & (Nn - 1);
  const float* cpb = cp + (size_t)b * 3 * Nn;
  float x0 = cpb[m], y0 = cpb[Nn + m], z0 = cpb[2 * Nn + m];
  float* Gb = G + (size_t)b * KT * Nn;
#pragma unroll
  for (int t = 0; t < KT; ++t) {
    int q = m + t - 4;
    q = q < 0 ? 0 : (q > Nn - 1 ? Nn - 1 : q);  // OOB value irrelevant (x==0 there)
    float dx = cpb[q] - x0;
    float dy = cpb[Nn + q] - y0;
    float dz = cpb[2 * Nn + q] - z0;
    Gb[(size_t)t * Nn + m] = __expf(-(dx * dx + dy * dy + dz * dz));  // sigma=1
  }
}

// ---------------- BN affine coefficients ---------------------------------------
__global__ void bncoeff(const float* __restrict__ sums,
                        const float* __restrict__ gamma,
                        const float* __restrict__ beta,
                        float* __restrict__ coeff) {
  int c = threadIdx.x;  // 128 threads
  const float inv = 1.0f / (float)((size_t)Bn * Nn);
  float mean = sums[c] * inv;
  float var = sums[128 + c] * inv - mean * mean;
  float a = gamma[c] * rsqrtf(var + 1e-5f);
  coeff[c] = a;
  coeff[128 + c] = beta[c] - mean * a;
}

__device__ __forceinline__ f16x8 scale8(f16x8 v, _Float16 g) {
  f16x8 r;
#pragma unroll
  for (int i = 0; i < 8; ++i) r[i] = v[i] * g;  // 4x v_pk_mul_f16
  return r;
}

// ---------------- fused weighted conv: tap-accumulating MFMA -------------------
// out[o,p] = sum_t W_t[o,:] . ( x[:, p+t-4] * g[p,t] )  -- g folded into B-frag,
// all taps accumulate in the same C registers. Waves tile 2(M)x2(N); per-wave
// register tile M64 x N128 (A-frag reuse 8x). launch_bounds(256,2): cap total
// regs at 256 (128 AGPR acc + <=128 arch) so 2 waves/SIMD are resident.
template <int TRANS>
__global__ __launch_bounds__(256, 2) void conv_mfma(
    const _Float16* __restrict__ Xin, const _Float16* __restrict__ W,
    const float* __restrict__ G, _Float16* __restrict__ Yout,
    float* __restrict__ sums, const float* __restrict__ coeff) {
  __shared__ __align__(16) _Float16 Xs[T_HALO * XROW];  // 71808 B
  __shared__ __align__(16) unsigned char aux[KT * GROW * 2];  // 4752 B: Gs, later red
  _Float16* Gs = (_Float16*)aux;
  float* red = (float*)aux;

  const int tid = threadIdx.x;
  const int b = blockIdx.x >> 8;
  const int p0 = (blockIdx.x & 255) * T_OUT;
  const int ch = tid & 15;

  // ---- stage X halo tile (rows r=0..263 <-> q = p0-4+r), zero OOB ----
#pragma unroll
  for (int pass = 0; pass < 17; ++pass) {
    int r = pass * 16 + (tid >> 4);
    if (r < T_HALO) {
      int q = p0 - 4 + r;
      f16x8 v = {0, 0, 0, 0, 0, 0, 0, 0};
      if (q >= 0 && q < Nn) {
        v = *(const f16x8*)(Xin + ((size_t)b * Nn + q) * Cn + ch * 8);
        if (TRANS) {
#pragma unroll
          for (int i = 0; i < 8; ++i) {
            float f = fmaxf(coeff[ch * 8 + i] * (float)v[i] + coeff[128 + ch * 8 + i], 0.f);
            v[i] = (_Float16)f;
          }
        }
      }
      *(f16x8*)(&Xs[r * XROW + ch * 8]) = v;
    }
  }
  // ---- stage G tile as f16 ----
  {
    const float* gb = G + (size_t)b * KT * Nn + p0;
    for (int i = tid; i < KT * 256; i += 256) {
      int t = i >> 8;
      int p = i & 255;
      Gs[t * GROW + p] = (_Float16)gb[(size_t)t * Nn + p];
    }
  }

  const int w = tid >> 6;
  const int lane = tid & 63;
  const int l15 = lane & 15;
  const int quad = lane >> 4;
  const int wm = w >> 1;   // M-stripe: channels wm*64 .. wm*64+63
  const int wn = w & 1;    // N-stripe: positions wn*128 .. wn*128+127

  f32x4 acc[4][8];
  const f32x4 z4 = {0.f, 0.f, 0.f, 0.f};
#pragma unroll
  for (int mt = 0; mt < 4; ++mt)
#pragma unroll
    for (int nt = 0; nt < 8; ++nt) acc[mt][nt] = z4;

  __syncthreads();

#pragma unroll 1
  for (int t = 0; t < KT; ++t) {
    // per-tap gaussian scalars for this lane's 8 position columns
    _Float16 gt[8];
#pragma unroll
    for (int nt = 0; nt < 8; ++nt)
      gt[nt] = Gs[t * GROW + wn * 128 + nt * 16 + l15];

    const _Float16* Wt = W + ((size_t)t << 14) + (wm * 64) * Cn;
#pragma unroll
    for (int ko = 0; ko < 4; ++ko) {
      f16x8 a[4];
#pragma unroll
      for (int mt = 0; mt < 4; ++mt)
        a[mt] = *(const f16x8*)(Wt + (mt * 16 + l15) * Cn + ko * 32 + quad * 8);
#pragma unroll
      for (int nt = 0; nt < 8; ++nt) {
        f16x8 bv = *(const f16x8*)(&Xs[(wn * 128 + nt * 16 + l15 + t) * XROW + ko * 32 + quad * 8]);
        bv = scale8(bv, gt[nt]);
#pragma unroll
        for (int mt = 0; mt < 4; ++mt)
          acc[mt][nt] = __builtin_amdgcn_mfma_f32_16x16x32_f16(a[mt], bv, acc[mt][nt], 0, 0, 0);
      }
    }
  }

  // ---- BN partial sums from f32 accumulators (shfl tree over l15) ----
  // channel of acc[mt][*][rg] = wm*64 + mt*16 + quad*4 + rg
  f32x4 s4[4], q4[4];
#pragma unroll
  for (int mt = 0; mt < 4; ++mt) {
#pragma unroll
    for (int rg = 0; rg < 4; ++rg) {
      float s = 0.f, q = 0.f;
#pragma unroll
      for (int nt = 0; nt < 8; ++nt) {
        float v = acc[mt][nt][rg];
        s += v;
        q += v * v;
      }
#pragma unroll
      for (int m = 1; m < 16; m <<= 1) {
        s += __shfl_xor(s, m);
        q += __shfl_xor(q, m);
      }
      s4[mt][rg] = s;
      q4[mt][rg] = q;
    }
  }
  __syncthreads();  // all waves done reading Xs/Gs; red (aliases Gs) free to write
  if (l15 == 0) {
#pragma unroll
    for (int mt = 0; mt < 4; ++mt) {
      int cbase = wm * 64 + mt * 16 + quad * 4;
      *(f32x4*)(&red[wn * 128 + cbase]) = s4[mt];
      *(f32x4*)(&red[256 + wn * 128 + cbase]) = q4[mt];
    }
  }

  // ---- epilogue: transpose via LDS (reuse Xs as Os[p][XROW]) ----
  _Float16* Os = Xs;
  // C/D layout: col(position) = l15, row(channel) = quad*4+rg
#pragma unroll
  for (int mt = 0; mt < 4; ++mt)
#pragma unroll
    for (int nt = 0; nt < 8; ++nt) {
      f16x4 o4;
#pragma unroll
      for (int rg = 0; rg < 4; ++rg) o4[rg] = (_Float16)acc[mt][nt][rg];
      *(f16x4*)(&Os[(wn * 128 + nt * 16 + l15) * XROW + wm * 64 + mt * 16 + quad * 4]) = o4;
    }
  __syncthreads();

  if (tid < 128) {
    atomicAdd(&sums[tid], red[tid] + red[128 + tid]);
    atomicAdd(&sums[128 + tid], red[256 + tid] + red[384 + tid]);
  }
#pragma unroll
  for (int pass = 0; pass < 16; ++pass) {
    int r = pass * 16 + (tid >> 4);
    f16x8 v = *(const f16x8*)(&Os[r * XROW + ch * 8]);
    *(f16x8*)(Yout + ((size_t)b * Nn + p0 + r) * Cn + ch * 8) = v;
  }
}

// ---------------- final: scatter + BN2 affine + residual + relu ----------------
// stage1: gather y2 rows -> f32 LDS tile (transposed write); stage2: coalesced
// float4 x-read + float4 out-write.
__global__ __launch_bounds__(256) void final_k(const _Float16* __restrict__ y2,
                                               const float* __restrict__ x,
                                               const int* __restrict__ reidx,
                                               const float* __restrict__ coeff,
                                               float* __restrict__ out) {
  __shared__ float ft[128 * FT];  // 33792 B
  int tid = threadIdx.x;
  int b = blockIdx.x >> 10;
  int n0 = (blockIdx.x & 1023) * 64;
  {
    int ch = tid & 15;
#pragma unroll
    for (int pass = 0; pass < 4; ++pass) {
      int r = pass * 16 + (tid >> 4);
      int m = reidx[(size_t)b * Nn + n0 + r];
      f16x8 v = *(const f16x8*)(y2 + ((size_t)b * Nn + m) * Cn + ch * 8);
#pragma unroll
      for (int k = 0; k < 8; ++k) ft[(ch * 8 + k) * FT + r] = (float)v[k];
    }
  }
  __syncthreads();
  int cc = tid >> 4;
  int j4 = (tid & 15) * 4;
#pragma unroll
  for (int pass = 0; pass < 8; ++pass) {
    int c = pass * 16 + cc;
    float a = coeff[c];
    float bb = coeff[128 + c];
    f32x2 v0 = *(const f32x2*)(&ft[c * FT + j4]);
    f32x2 v1 = *(const f32x2*)(&ft[c * FT + j4 + 2]);
    size_t gi = ((size_t)b * Cn + c) * Nn + n0 + j4;
    f32x4 xv = *(const f32x4*)(&x[gi]);
    f32x4 r;
    r.x = fmaxf(a * v0.x + bb + xv.x, 0.f);
    r.y = fmaxf(a * v0.y + bb + xv.y, 0.f);
    r.z = fmaxf(a * v1.x + bb + xv.z, 0.f);
    r.w = fmaxf(a * v1.y + bb + xv.w, 0.f);
    *(f32x4*)(&out[gi]) = r;
  }
}

extern "C" void kernel_launch(void* const* d_in, const int* in_sizes, int n_in,
                              void* d_out, int out_size, void* d_ws, size_t ws_size,
                              hipStream_t stream) {
  (void)in_sizes; (void)n_in; (void)out_size; (void)ws_size;
  const float* x = (const float*)d_in[0];
  const float* coords = (const float*)d_in[1];
  const int* indices = (const int*)d_in[2];
  const int* reindices = (const int*)d_in[3];
  const float* w1 = (const float*)d_in[4];
  const float* gamma1 = (const float*)d_in[5];
  const float* beta1 = (const float*)d_in[6];
  const float* w2 = (const float*)d_in[7];
  const float* gamma2 = (const float*)d_in[8];
  const float* beta2 = (const float*)d_in[9];
  float* out = (float*)d_out;

  // workspace: [0,64MB) xp -> y2 ; then sums1/sums2/coeff1/coeff2 ; then Wr f16
  char* ws = (char*)d_ws;
  const size_t BUF0 = (size_t)Bn * Nn * Cn * sizeof(_Float16);  // 64 MB
  _Float16* buf0 = (_Float16*)ws;
  float* sums1 = (float*)(ws + BUF0);
  float* sums2 = sums1 + 256;
  float* coeff1 = sums1 + 512;
  float* coeff2 = sums1 + 768;
  _Float16* Wr = (_Float16*)(ws + BUF0 + 4096);  // 2*9*128*128 f16 = 576 KB

  // d_out doubles as scratch until the final kernel: y1 f16 [0,64MB), cp, G
  char* dob = (char*)d_out;
  _Float16* y1 = (_Float16*)dob;
  float* cp = (float*)(dob + BUF0);                               // 3 MB
  float* G = (float*)(dob + BUF0 + (size_t)Bn * 3 * Nn * 4);      // 9 MB

  hipMemsetAsync(sums1, 0, 512 * sizeof(float), stream);

  repack_w<<<1152, 256, 0, stream>>>(w1, w2, Wr);
  gather_x<<<Bn * 1024, 256, 0, stream>>>(x, reindices, buf0);
  gather_cp<<<1024, 256, 0, stream>>>(coords, indices, cp);
  compute_g<<<1024, 256, 0, stream>>>(cp, G);

  conv_mfma<0><<<Bn * 256, 256, 0, stream>>>(buf0, Wr, G, y1, sums1, nullptr);
  bncoeff<<<1, 128, 0, stream>>>(sums1, gamma1, beta1, coeff1);
  conv_mfma<1><<<Bn * 256, 256, 0, stream>>>(y1, Wr + (size_t)KT * Cn * Cn, G,
                                             buf0, sums2, coeff1);
  bncoeff<<<1, 128, 0, stream>>>(sums2, gamma2, beta2, coeff2);
  final_k<<<Bn * 1024, 256, 0, stream>>>(buf0, x, reindices, coeff2, out);
}